// Round 21
// baseline (93.144 us; speedup 1.0000x reference)
//
#include <hip/hip_runtime.h>

#define NEWL 150
#define EMBD 64
#define NCOL 256
#define CIMU 48
#define CEMG 16

#define KIMU (NEWL * CIMU)  // 7200
#define KEMG (NEWL * CEMG)  // 2400
#define KSTI 225            // total 32-wide k-steps imu
#define KSTE 75             // total k-steps emg
#define NCI 5               // imu s-chunks (15 groups each)
#define NCE 3               // emg s-chunks (9/8/8 groups)

typedef __bf16 bf16x8_t __attribute__((ext_vector_type(8)));
typedef __bf16 bf16x4_t __attribute__((ext_vector_type(4)));
typedef float f32x4_t __attribute__((ext_vector_type(4)));

__device__ __forceinline__ f32x4_t mfma16(bf16x8_t a, bf16x8_t b, f32x4_t c) {
  return __builtin_amdgcn_mfma_f32_16x16x32_bf16(a, b, c, 0, 0, 0);
}

// ---------- K0: merged combined-weights (one w_proj read) + bias partials.
// W_pack[cb][ks][lane=h*16+(col&15)][u], k = ks*32 + h*8 + u  (verified R7/R8)
template <int C, int KST>
__device__ __forceinline__ void wcomb_body(const float* __restrict__ wemb,
                                           const float* wreg,
                                           __bf16* __restrict__ wpk, int s, int j) {
  const int cb = j >> 4, lr = j & 15;
#pragma unroll
  for (int q = 0; q < C / 8; ++q) {
    const int kq = (s * C) / 8 + q;
    const int ks = kq >> 2, h = kq & 3;
    bf16x8_t tv;
#pragma unroll
    for (int u = 0; u < 8; ++u) {
      const float* we = wemb + (q * 8 + u) * EMBD;
      float acc = 0.f;
#pragma unroll
      for (int e = 0; e < EMBD; ++e) acc = fmaf(we[e], wreg[e], acc);
      tv[u] = (__bf16)acc;
    }
    *(bf16x8_t*)(wpk + (((size_t)cb * KST + ks) * 64 + h * 16 + lr) * 8) = tv;
  }
}

__global__ __launch_bounds__(256) void wcomb_kernel(
    const float* __restrict__ w_emb_imu, const float* __restrict__ w_emb_emg,
    const float* __restrict__ b_emb_imu, const float* __restrict__ b_emb_emg,
    const float* __restrict__ w_proj,
    __bf16* __restrict__ wpk_imu, __bf16* __restrict__ wpk_emg,
    float* __restrict__ bpart) {
  const int s = blockIdx.x, j = threadIdx.x;
  const float* wp_base = w_proj + (size_t)s * EMBD * NCOL + j;
  float wreg[EMBD];
#pragma unroll
  for (int e = 0; e < EMBD; ++e) wreg[e] = wp_base[(size_t)e * NCOL];
  float bi = 0.f, be = 0.f;
#pragma unroll
  for (int e = 0; e < EMBD; ++e) {
    bi = fmaf(b_emb_imu[e], wreg[e], bi);
    be = fmaf(b_emb_emg[e], wreg[e], be);
  }
  bpart[(size_t)s * NCOL + j] = bi;
  bpart[((size_t)NEWL + s) * NCOL + j] = be;
  wcomb_body<CIMU, KSTI>(w_emb_imu, wreg, wpk_imu, s, j);
  wcomb_body<CEMG, KSTE>(w_emb_emg, wreg, wpk_emg, s, j);
}

// ---------- K1: producer-consumer fused interp+GEMM. 512 threads:
// waves 0-3 consume (MFMA, 4 col-planes each), waves 4-7 produce
// (gather+lerp+ring-write). 4-slot LDS ring + generation flags, NO barriers
// in the loop -> producer gathers pipeline across groups (no vmcnt drain).
__global__ __launch_bounds__(512, 2) void fused_kernel(
    const float* __restrict__ x_imu, const float* __restrict__ x_emg,
    const int* __restrict__ lens,
    const __bf16* __restrict__ wpk_imu, const __bf16* __restrict__ wpk_emg,
    const float* __restrict__ b_proj, const float* __restrict__ bpart,
    float* __restrict__ p_imu, float* __restrict__ p_emg,
    float* __restrict__ bias, int B, int T) {
  const int bid = blockIdx.x;
  const int span = B >> 5;               // 64 m-tiles per chunk
  const int nblk = (NCE + NCI) * span;   // 512 compute blocks
  if (bid == nblk) {  // bias tail block
    const int j = threadIdx.x;
    if (j < NCOL) {
#pragma unroll
      for (int m = 0; m < 2; ++m) {
        float acc = b_proj[j];
        for (int s = 0; s < NEWL; ++s)
          acc += bpart[((size_t)m * NEWL + s) * NCOL + j];
        bias[m * NCOL + j] = acc;
      }
    }
    return;
  }

  __shared__ __bf16 ring[4][2][3][512];  // 4 slots x [row-plane][ks][lane*8] = 24KB
  __shared__ int fprod[4][4];            // [slot][producer wave]: last group staged
  __shared__ int fcons[4][4];            // [slot][consumer wave]: last group consumed

  const int tid = threadIdx.x;
  if (tid < 16) ((int*)fprod)[tid] = -1;
  else if (tid < 32) ((int*)fcons)[tid - 16] = -1;
  __syncthreads();  // only barrier in the kernel
  volatile int* vfp = (volatile int*)&fprod[0][0];
  volatile int* vfc = (volatile int*)&fcons[0][0];

  const int wv = tid >> 6, l = tid & 63;

  const int cs = bid / span;
  const int mt = bid - cs * span;
  const bool is_imu = cs >= NCE;
  const int c = is_imu ? cs - NCE : cs;

  int g0, NG;
  if (is_imu) { g0 = 15 * c; NG = 15; }
  else        { g0 = (c == 0) ? 0 : (9 + 8 * (c - 1)); NG = c ? 8 : 9; }
  const int ks0 = 3 * g0;
  const int sb = is_imu ? 2 * g0 : 6 * g0;

  const __bf16* Wp = is_imu ? wpk_imu : wpk_emg;
  const int KST = is_imu ? KSTI : KSTE;
  float* P = is_imu ? (p_imu + (size_t)c * B * NCOL) : (p_emg + (size_t)c * B * NCOL);

  if (wv < 4) {
    // ================= CONSUMER (waves 0-3) =================
    const int cw = wv;
    const int lh = l >> 4, lr = l & 15;
    const size_t PS = (size_t)KST * 512;
    const __bf16* bg = Wp + ((size_t)(cw * 4) * KST + ks0) * 512 + l * 8;

    bf16x8_t bB[12];  // 4 col-planes x 3 ksteps
    f32x4_t acc[2][4];
#pragma unroll
    for (int rp = 0; rp < 2; ++rp)
#pragma unroll
      for (int cp = 0; cp < 4; ++cp) acc[rp][cp] = (f32x4_t){0.f, 0.f, 0.f, 0.f};

    for (int g = 0; g < NG; ++g) {
      // B prefetch for g BEFORE polling: latency hides under the wait
      {
        const __bf16* pb = bg + (size_t)(g * 3) * 512;
#pragma unroll
        for (int cp = 0; cp < 4; ++cp)
#pragma unroll
          for (int ks = 0; ks < 3; ++ks)
            bB[cp * 3 + ks] =
                *(const bf16x8_t*)(pb + (size_t)cp * PS + (size_t)ks * 512);
      }
      const int slot = g & 3;
      int seen = 0;
#pragma unroll
      for (int pw = 0; pw < 4; ++pw) {
        int v = vfp[slot * 4 + pw];
        while (v < g) { __builtin_amdgcn_s_sleep(1); v = vfp[slot * 4 + pw]; }
        seen += v;
      }
      // data-dependent base: poff == 0 but forces reads after the poll
      const int poff = seen - 4 * g;
      const __bf16* ab = &ring[slot][0][0][0] + poff;
#pragma unroll
      for (int ks = 0; ks < 3; ++ks) {
        const bf16x8_t a0 = *(const bf16x8_t*)(ab + (0 * 3 + ks) * 512 + l * 8);
        const bf16x8_t a1 = *(const bf16x8_t*)(ab + (1 * 3 + ks) * 512 + l * 8);
#pragma unroll
        for (int cp = 0; cp < 4; ++cp) {
          acc[0][cp] = mfma16(a0, bB[cp * 3 + ks], acc[0][cp]);
          acc[1][cp] = mfma16(a1, bB[cp * 3 + ks], acc[1][cp]);
        }
      }
      __builtin_amdgcn_s_waitcnt(0xC07F);   // lgkmcnt(0): A-frag reads done
      __builtin_amdgcn_sched_barrier(0);
      if (l == 0) vfc[slot * 4 + cw] = g;
    }
    // epilogue
    float* Pb = P + (size_t)(mt * 32 + lh * 4) * NCOL + cw * 64 + lr;
#pragma unroll
    for (int rp = 0; rp < 2; ++rp)
#pragma unroll
      for (int cp = 0; cp < 4; ++cp)
#pragma unroll
        for (int jj = 0; jj < 4; ++jj)
          Pb[(size_t)(rp * 16 + jj) * NCOL + cp * 16] = acc[rp][cp][jj];
    return;
  }

  // ================= PRODUCER (waves 4-7) =================
  const int pw = wv - 4;
  const int ptid = tid - 256;  // 0..255

#define P_WAITC(g_, POFF) int POFF;                                             \
  {                                                                             \
    const int slot_ = (g_) & 3;                                                 \
    int seenc_ = 0;                                                             \
    _Pragma("unroll")                                                           \
    for (int cw_ = 0; cw_ < 4; ++cw_) {                                         \
      int v_ = vfc[slot_ * 4 + cw_];                                            \
      while (v_ < (g_) - 4) { __builtin_amdgcn_s_sleep(1);                      \
                              v_ = vfc[slot_ * 4 + cw_]; }                      \
      seenc_ += v_;                                                             \
    }                                                                           \
    POFF = seenc_ - (((g_) >= 4) ? 4 * ((g_) - 4) : -4);                        \
  }

#define P_FLAG(g_) do {                                                         \
    __builtin_amdgcn_s_waitcnt(0xC07F);                                         \
    __builtin_amdgcn_sched_barrier(0);                                          \
    if (l == 0) vfp[((g_) & 3) * 4 + pw] = (g_);                                \
  } while (0)

  if (is_imu) {
    // 4 thr/(b,s): q quarter of row, each thread reads BOTH rows (R11 map)
    const int q = ptid & 3, pair = ptid >> 2;
    const int b4 = pair & 31, sl = pair >> 5;
    const int b_g = mt * 32 + b4;
    const int lenv = lens[b_g];
    const float scale = (float)lenv * (1.0f / 150.0f);
    const float* xg = x_imu + (size_t)b_g * T * CIMU + q * 4;
    float grA[24], grB[24];
    float wA, wB;

#define PI_ISSUE(g_, GR, WS) do {                                               \
    const int s_ = sb + (g_) * 2 + sl;                                          \
    float src_ = fmaxf(((float)s_ + 0.5f) * scale - 0.5f, 0.0f);                \
    int i0_ = min((int)src_, lenv - 1);                                         \
    int i1_ = min(i0_ + 1, lenv - 1);                                           \
    WS = src_ - (float)i0_;                                                     \
    const float* r0_ = xg + (size_t)i0_ * CIMU;                                 \
    const float* r1_ = xg + (size_t)i1_ * CIMU;                                 \
    _Pragma("unroll")                                                           \
    for (int t = 0; t < 3; ++t) {                                               \
      float4 v_ = *(const float4*)(r0_ + t * 16);                               \
      GR[t * 4 + 0] = v_.x; GR[t * 4 + 1] = v_.y;                               \
      GR[t * 4 + 2] = v_.z; GR[t * 4 + 3] = v_.w;                               \
      float4 u_ = *(const float4*)(r1_ + t * 16);                               \
      GR[12 + t * 4 + 0] = u_.x; GR[12 + t * 4 + 1] = u_.y;                     \
      GR[12 + t * 4 + 2] = u_.z; GR[12 + t * 4 + 3] = u_.w;                     \
    }                                                                           \
  } while (0)

#define PI_WRITE(g_, GR, WS, POFF) do {                                         \
    __bf16* wb_ = &ring[(g_) & 3][0][0][0] + (POFF);                            \
    const float wg_ = WS, om_ = 1.0f - wg_;                                     \
    _Pragma("unroll")                                                           \
    for (int t = 0; t < 3; ++t) {                                               \
      bf16x4_t o_;                                                              \
      _Pragma("unroll")                                                         \
      for (int u = 0; u < 4; ++u)                                               \
        o_[u] = (__bf16)(GR[t * 4 + u] * om_ + GR[12 + t * 4 + u] * wg_);       \
      const int kq_ = sl * 6 + t * 2 + (q >> 1);                                \
      *(bf16x4_t*)(wb_ + ((b4 >> 4) * 3 + (kq_ >> 2)) * 512 +                   \
                   ((kq_ & 3) * 16 + (b4 & 15)) * 8 + (q & 1) * 4) = o_;        \
    }                                                                           \
  } while (0)

    PI_ISSUE(0, grA, wA);
    for (int gp = 0; gp < 15; gp += 2) {
      if (gp >= NG) break;
      if (gp + 1 < NG) PI_ISSUE(gp + 1, grB, wB);
      { P_WAITC(gp, poc0); PI_WRITE(gp, grA, wA, poc0); }
      P_FLAG(gp);
      if (gp + 1 >= NG) break;
      if (gp + 2 < NG) PI_ISSUE(gp + 2, grA, wA);
      { P_WAITC(gp + 1, poc1); PI_WRITE(gp + 1, grB, wB, poc1); }
      P_FLAG(gp + 1);
    }
  } else {
    // emg: 1 thr/(b,s), 192 active threads (waves 4-6); wave 7 flags only
    const bool pact = ptid < 192;
    const int ble = pact ? (ptid / 6) : 0;
    const int se = pact ? (ptid - (ptid / 6) * 6) : 0;
    const int b_g = mt * 32 + ble;
    int lenv = 1;
    float scale = 0.f;
    if (pact) { lenv = lens[b_g]; scale = (float)lenv * (1.0f / 150.0f); }
    float grA[32], grB[32];
    float wA, wB;

#define PE_ISSUE(g_, GR, WS) do { if (pact) {                                   \
    const int s_ = sb + (g_) * 6 + se;                                          \
    float src_ = fmaxf(((float)s_ + 0.5f) * scale - 0.5f, 0.0f);                \
    int i0_ = min((int)src_, lenv - 1);                                         \
    int i1_ = min(i0_ + 1, lenv - 1);                                           \
    WS = src_ - (float)i0_;                                                     \
    const float* p0_ = x_emg + ((size_t)b_g * T + i0_) * CEMG;                  \
    const float* p1_ = x_emg + ((size_t)b_g * T + i1_) * CEMG;                  \
    _Pragma("unroll")                                                           \
    for (int t = 0; t < 4; ++t) {                                               \
      float4 v_ = *(const float4*)(p0_ + t * 4);                                \
      GR[t * 4 + 0] = v_.x; GR[t * 4 + 1] = v_.y;                               \
      GR[t * 4 + 2] = v_.z; GR[t * 4 + 3] = v_.w;                               \
      float4 u_ = *(const float4*)(p1_ + t * 4);                                \
      GR[16 + t * 4 + 0] = u_.x; GR[16 + t * 4 + 1] = u_.y;                     \
      GR[16 + t * 4 + 2] = u_.z; GR[16 + t * 4 + 3] = u_.w;                     \
    }                                                                           \
  } } while (0)

#define PE_WRITE(g_, GR, WS, POFF) do { if (pact) {                             \
    __bf16* wb_ = &ring[(g_) & 3][0][0][0] + (POFF);                            \
    const float wg_ = WS, om_ = 1.0f - wg_;                                     \
    _Pragma("unroll")                                                           \
    for (int t2 = 0; t2 < 2; ++t2) {                                            \
      bf16x8_t o_;                                                              \
      _Pragma("unroll")                                                         \
      for (int u = 0; u < 8; ++u)                                               \
        o_[u] = (__bf16)(GR[t2 * 8 + u] * om_ + GR[16 + t2 * 8 + u] * wg_);     \
      const int kq_ = se * 2 + t2;                                              \
      *(bf16x8_t*)(wb_ + ((ble >> 4) * 3 + (kq_ >> 2)) * 512 +                  \
                   ((kq_ & 3) * 16 + (ble & 15)) * 8) = o_;                     \
    }                                                                           \
  } } while (0)

    PE_ISSUE(0, grA, wA);
    for (int gp = 0; gp < 15; gp += 2) {
      if (gp >= NG) break;
      if (gp + 1 < NG) PE_ISSUE(gp + 1, grB, wB);
      { P_WAITC(gp, poc0); PE_WRITE(gp, grA, wA, poc0); }
      P_FLAG(gp);
      if (gp + 1 >= NG) break;
      if (gp + 2 < NG) PE_ISSUE(gp + 2, grA, wA);
      { P_WAITC(gp + 1, poc1); PE_WRITE(gp + 1, grB, wB, poc1); }
      P_FLAG(gp + 1);
    }
  }
#undef P_WAITC
#undef P_FLAG
#undef PI_ISSUE
#undef PI_WRITE
#undef PE_ISSUE
#undef PE_WRITE
}

// ---------- K2: sum split-K partials + bias -> d_out
__global__ __launch_bounds__(256) void combine_kernel(
    const float* __restrict__ bias, const float* __restrict__ p_imu,
    const float* __restrict__ p_emg, float* __restrict__ out, int B) {
  const int b = blockIdx.x, m = blockIdx.y, j = threadIdx.x;
  const size_t n = (size_t)B * NCOL;
  const size_t o = (size_t)b * NCOL + j;
  if (m == 0) {
    float v = bias[j];
#pragma unroll
    for (int c = 0; c < NCI; ++c) v += p_imu[c * n + o];
    out[o] = v;
  } else {
    float v = bias[NCOL + j];
#pragma unroll
    for (int c = 0; c < NCE; ++c) v += p_emg[c * n + o];
    out[n + o] = v;
  }
}

extern "C" void kernel_launch(void* const* d_in, const int* in_sizes, int n_in,
                              void* d_out, int out_size, void* d_ws, size_t ws_size,
                              hipStream_t stream) {
  const float* x_imu     = (const float*)d_in[0];
  const float* x_emg     = (const float*)d_in[1];
  const int*   lens      = (const int*)d_in[2];
  const float* w_emb_imu = (const float*)d_in[3];
  const float* b_emb_imu = (const float*)d_in[4];
  const float* w_emb_emg = (const float*)d_in[5];
  const float* b_emb_emg = (const float*)d_in[6];
  const float* w_proj    = (const float*)d_in[7];
  const float* b_proj    = (const float*)d_in[8];
  float* out = (float*)d_out;

  const int B = in_sizes[2];
  const int T = in_sizes[0] / (B * CIMU);

  char* ws = (char*)d_ws;
  __bf16* wpk_imu = (__bf16*)ws;  ws += (size_t)NCOL * KIMU * 2;
  __bf16* wpk_emg = (__bf16*)ws;  ws += (size_t)NCOL * KEMG * 2;
  float*  bias    = (float*)ws;   ws += 2 * NCOL * 4;
  float*  bpart   = (float*)ws;   ws += (size_t)2 * NEWL * NCOL * 4;
  float*  p_imu   = (float*)ws;   ws += (size_t)NCI * B * NCOL * 4;
  float*  p_emg   = (float*)ws;   ws += (size_t)NCE * B * NCOL * 4;

  wcomb_kernel<<<NEWL, 256, 0, stream>>>(w_emb_imu, w_emb_emg, b_emb_imu,
                                         b_emb_emg, w_proj, wpk_imu, wpk_emg,
                                         bpart);
  const int span = B >> 5;                        // 64
  const int nblk = (NCE + NCI) * span + 1;        // 513
  fused_kernel<<<nblk, 512, 0, stream>>>(x_imu, x_emg, lens, wpk_imu, wpk_emg,
                                         b_proj, bpart, p_imu, p_emg, bias, B, T);
  combine_kernel<<<dim3(B, 2), 256, 0, stream>>>(bias, p_imu, p_emg, out, B);
}

// Round 22
// 84.307 us; speedup vs baseline: 1.1048x; 1.1048x over previous
//
#include <hip/hip_runtime.h>

#define NEWL 150
#define EMBD 64
#define NCOL 256
#define CIMU 48
#define CEMG 16

#define KIMU (NEWL * CIMU)  // 7200
#define KEMG (NEWL * CEMG)  // 2400
#define KSTI 225            // total 32-wide k-steps imu
#define KSTE 75             // total k-steps emg
#define NCI 12              // imu s-chunks (7/7/7/6x9 groups), 64-row tiles
#define NCE 2               // emg s-chunks (13/12 groups), 32-row tiles

typedef __bf16 bf16x8_t __attribute__((ext_vector_type(8)));
typedef __bf16 bf16x4_t __attribute__((ext_vector_type(4)));
typedef float f32x4_t __attribute__((ext_vector_type(4)));

__device__ __forceinline__ f32x4_t mfma16(bf16x8_t a, bf16x8_t b, f32x4_t c) {
  return __builtin_amdgcn_mfma_f32_16x16x32_bf16(a, b, c, 0, 0, 0);
}

// ---------- K0: combined weights packed in MFMA B-fragment order + bias partials.
// W_pack[cb][ks][lane=h*16+(col&15)][u]  where k = ks*32 + h*8 + u
template <int C, int KST>
__device__ void wcomb_body(const float* __restrict__ wemb,
                           const float* __restrict__ wreg_src,
                           __bf16* __restrict__ wpk, int s, int j) {
  float wreg[EMBD];
#pragma unroll
  for (int e = 0; e < EMBD; ++e) wreg[e] = wreg_src[(size_t)e * NCOL];
  const int cb = j >> 4, lr = j & 15;
#pragma unroll
  for (int q = 0; q < C / 8; ++q) {
    const int kq = (s * C) / 8 + q;
    const int ks = kq >> 2, h = kq & 3;
    bf16x8_t tv;
#pragma unroll
    for (int u = 0; u < 8; ++u) {
      const float* we = wemb + (q * 8 + u) * EMBD;
      float acc = 0.f;
#pragma unroll
      for (int e = 0; e < EMBD; ++e) acc = fmaf(we[e], wreg[e], acc);
      tv[u] = (__bf16)acc;
    }
    *(bf16x8_t*)(wpk + (((size_t)cb * KST + ks) * 64 + h * 16 + lr) * 8) = tv;
  }
}

__global__ __launch_bounds__(256) void wcomb_kernel(
    const float* __restrict__ w_emb_imu, const float* __restrict__ w_emb_emg,
    const float* __restrict__ b_emb_imu, const float* __restrict__ b_emb_emg,
    const float* __restrict__ w_proj,
    __bf16* __restrict__ wpk_imu, __bf16* __restrict__ wpk_emg,
    float* __restrict__ bpart) {
  const int s = blockIdx.x;   // 0..149
  const int m = blockIdx.y;   // 0 = imu, 1 = emg
  const int j = threadIdx.x;  // output column 0..255
  const float* wp_base = w_proj + (size_t)s * EMBD * NCOL + j;
  const float* be = (m == 0) ? b_emb_imu : b_emb_emg;
  float bacc = 0.f;
#pragma unroll
  for (int e = 0; e < EMBD; ++e) bacc = fmaf(be[e], wp_base[(size_t)e * NCOL], bacc);
  bpart[((size_t)m * NEWL + s) * NCOL + j] = bacc;
  if (m == 0)
    wcomb_body<CIMU, KSTI>(w_emb_imu, wp_base, wpk_imu, s, j);
  else
    wcomb_body<CEMG, KSTE>(w_emb_emg, wp_base, wpk_emg, s, j);
}

// ---------- K1: fused ragged-interp + MFMA GEMM, 512-thread blocks.
// imu blocks: 64-row x 256-col tiles (halves B-traffic per output; the B
// re-read was the dominant line-lookup term). emg blocks: 32-row (R17 shape).
// Distance-1 pipeline, static slots, __syncthreads.
__global__ __launch_bounds__(512, 2) void fused_kernel(
    const float* __restrict__ x_imu, const float* __restrict__ x_emg,
    const int* __restrict__ lens,
    const __bf16* __restrict__ wpk_imu, const __bf16* __restrict__ wpk_emg,
    const float* __restrict__ b_proj, const float* __restrict__ bpart,
    float* __restrict__ p_imu, float* __restrict__ p_emg,
    float* __restrict__ bias, int B, int T) {
  const int bid = blockIdx.x;
  const int spanE = B >> 5;              // 64 emg tiles per chunk (32-row)
  const int spanI = B >> 6;              // 32 imu tiles per chunk (64-row)
  const int nblk = NCE * spanE + NCI * spanI;  // 128 + 384 = 512
  if (bid == nblk) {  // bias tail block
    const int j = threadIdx.x;
    if (j < NCOL) {
#pragma unroll
      for (int m = 0; m < 2; ++m) {
        float acc = b_proj[j];
        for (int s = 0; s < NEWL; ++s)
          acc += bpart[((size_t)m * NEWL + s) * NCOL + j];
        bias[m * NCOL + j] = acc;
      }
    }
    return;
  }

  __shared__ __bf16 lds[2][4][3][512];  // [buf][row-plane(16r)][ks][lane*8] = 24KB

  const int tid = threadIdx.x;
  const int wv = tid >> 6, l = tid & 63;
  const bool is_imu = bid >= NCE * spanE;

  if (is_imu) {
    // ================= IMU: 64-row tile =================
    const int u0 = bid - NCE * spanE;
    const int c = u0 >> 5, mt = u0 & 31;
    int g0, NG;
    if (c < 3) { g0 = 7 * c; NG = 7; }
    else       { g0 = 21 + 6 * (c - 3); NG = 6; }
    const int ks0 = 3 * g0;
    const int sb = 2 * g0;
    float* P = p_imu + (size_t)c * B * NCOL;
    const size_t PS = (size_t)KSTI * 512;
    const __bf16* bg = wpk_imu + ((size_t)(wv * 2) * KSTI + ks0) * 512 + l * 8;

    // gather: 4 thr/(b,s): q=tid&3 quarter, sl=(tid>>2)&1 s-index, b6=tid>>3
    const int q = tid & 3, sl = (tid >> 2) & 1, b6 = tid >> 3;
    const int b_g = mt * 64 + b6;
    const int lenv = lens[b_g];
    const float scale = (float)lenv * (1.0f / 150.0f);
    const float* xg = x_imu + (size_t)b_g * T * CIMU + q * 4;

    float gr[24];   // both rows, quarter q (12 + 12)
    float wS;
    bf16x8_t bB[6]; // 2 col-planes x 3 ksteps (24 VGPR)
    f32x4_t acc[4][2];
#pragma unroll
    for (int rp = 0; rp < 4; ++rp)
#pragma unroll
      for (int cp = 0; cp < 2; ++cp) acc[rp][cp] = (f32x4_t){0.f, 0.f, 0.f, 0.f};

#define ISSUE_GI(g2) do {                                                       \
    const int s_ = sb + (g2) * 2 + sl;                                          \
    float src_ = fmaxf(((float)s_ + 0.5f) * scale - 0.5f, 0.0f);                \
    int i0_ = min((int)src_, lenv - 1);                                         \
    int i1_ = min(i0_ + 1, lenv - 1);                                           \
    wS = src_ - (float)i0_;                                                     \
    const float* r0_ = xg + (size_t)i0_ * CIMU;                                 \
    const float* r1_ = xg + (size_t)i1_ * CIMU;                                 \
    _Pragma("unroll")                                                           \
    for (int t = 0; t < 3; ++t) {                                               \
      float4 v_ = *(const float4*)(r0_ + t * 16);                               \
      gr[t * 4 + 0] = v_.x; gr[t * 4 + 1] = v_.y;                               \
      gr[t * 4 + 2] = v_.z; gr[t * 4 + 3] = v_.w;                               \
      float4 u_ = *(const float4*)(r1_ + t * 16);                               \
      gr[12 + t * 4 + 0] = u_.x; gr[12 + t * 4 + 1] = u_.y;                     \
      gr[12 + t * 4 + 2] = u_.z; gr[12 + t * 4 + 3] = u_.w;                     \
    }                                                                           \
  } while (0)

#define LERP_WI(BUF) do {                                                       \
    const float wg_ = wS, om_ = 1.0f - wg_;                                     \
    _Pragma("unroll")                                                           \
    for (int t = 0; t < 3; ++t) {                                               \
      bf16x4_t o_;                                                              \
      _Pragma("unroll")                                                         \
      for (int u = 0; u < 4; ++u)                                               \
        o_[u] = (__bf16)(gr[t * 4 + u] * om_ + gr[12 + t * 4 + u] * wg_);       \
      const int kq_ = sl * 6 + t * 2 + (q >> 1);                                \
      *(bf16x4_t*)(&lds[BUF][b6 >> 4][kq_ >> 2]                                 \
                       [((kq_ & 3) * 16 + (b6 & 15)) * 8 + (q & 1) * 4]) = o_;  \
    }                                                                           \
  } while (0)

#define ISSUE_B(g1) do {                                                        \
    const __bf16* pb_ = bg + (size_t)((g1) * 3) * 512;                          \
    _Pragma("unroll")                                                           \
    for (int ks = 0; ks < 3; ++ks) {                                            \
      bB[ks * 2 + 0] = *(const bf16x8_t*)(pb_ + (size_t)ks * 512);              \
      bB[ks * 2 + 1] = *(const bf16x8_t*)(pb_ + PS + (size_t)ks * 512);         \
    }                                                                           \
  } while (0)

#define COMPUTE_I(Pp) do {                                                      \
    _Pragma("unroll")                                                           \
    for (int ks = 0; ks < 3; ++ks) {                                            \
      bf16x8_t a0_ = *(const bf16x8_t*)(&lds[Pp][0][ks][l * 8]);                \
      bf16x8_t a1_ = *(const bf16x8_t*)(&lds[Pp][1][ks][l * 8]);                \
      bf16x8_t a2_ = *(const bf16x8_t*)(&lds[Pp][2][ks][l * 8]);                \
      bf16x8_t a3_ = *(const bf16x8_t*)(&lds[Pp][3][ks][l * 8]);                \
      acc[0][0] = mfma16(a0_, bB[ks * 2 + 0], acc[0][0]);                       \
      acc[0][1] = mfma16(a0_, bB[ks * 2 + 1], acc[0][1]);                       \
      acc[1][0] = mfma16(a1_, bB[ks * 2 + 0], acc[1][0]);                       \
      acc[1][1] = mfma16(a1_, bB[ks * 2 + 1], acc[1][1]);                       \
      acc[2][0] = mfma16(a2_, bB[ks * 2 + 0], acc[2][0]);                       \
      acc[2][1] = mfma16(a2_, bB[ks * 2 + 1], acc[2][1]);                       \
      acc[3][0] = mfma16(a3_, bB[ks * 2 + 0], acc[3][0]);                       \
      acc[3][1] = mfma16(a3_, bB[ks * 2 + 1], acc[3][1]);                       \
    }                                                                           \
  } while (0)

    ISSUE_GI(0); LERP_WI(0); ISSUE_B(0);
    __syncthreads();
    for (int p = 0; p < NG; ++p) {
      const int more = (p + 1 < NG);
      if (more) ISSUE_GI(p + 1);
      COMPUTE_I(p & 1);
      if (more) ISSUE_B(p + 1);
      if (more) LERP_WI((p + 1) & 1);
      __syncthreads();
    }
    const int lh = l >> 4, lr = l & 15;
    float* Pb = P + (size_t)(mt * 64 + lh * 4) * NCOL + wv * 32 + lr;
#pragma unroll
    for (int rp = 0; rp < 4; ++rp)
#pragma unroll
      for (int cp = 0; cp < 2; ++cp)
#pragma unroll
        for (int jj = 0; jj < 4; ++jj)
          Pb[(size_t)(rp * 16 + jj) * NCOL + cp * 16] = acc[rp][cp][jj];
#undef ISSUE_GI
#undef LERP_WI
#undef ISSUE_B
#undef COMPUTE_I
  } else {
    // ================= EMG: 32-row tile (R17 shape) =================
    const int c = bid / spanE, mt = bid - c * spanE;
    const int g0 = (c == 0) ? 0 : 13;
    const int NG = c ? 12 : 13;
    const int ks0 = 3 * g0;
    const int sb = 6 * g0;
    float* P = p_emg + (size_t)c * B * NCOL;
    const size_t PS = (size_t)KSTE * 512;
    const __bf16* bg = wpk_emg + ((size_t)(wv * 2) * KSTE + ks0) * 512 + l * 8;

    // 2 thr/(b,s): pid_e=tid>>1 (ble=pid_e/6, se=pid_e%6), row=tid&1; tid<384
    const int pid_e = tid >> 1;
    const int ble = pid_e / 6, se = pid_e - ble * 6, rowe = tid & 1;
    const bool act = tid < 384;
    const int b_g = mt * 32 + (act ? ble : 0);
    int lenv = 1;
    float scale = 0.f;
    if (act) { lenv = lens[b_g]; scale = (float)lenv * (1.0f / 150.0f); }

    float gr[16];
    float wS;
    bf16x8_t bB[6];
    f32x4_t acc00 = {0.f, 0.f, 0.f, 0.f}, acc01 = acc00, acc10 = acc00, acc11 = acc00;

#define ISSUE_GE(g2) do { if (act) {                                            \
    const int s_ = sb + (g2) * 6 + se;                                          \
    float src_ = fmaxf(((float)s_ + 0.5f) * scale - 0.5f, 0.0f);                \
    int i0_ = min((int)src_, lenv - 1);                                         \
    int i1_ = min(i0_ + 1, lenv - 1);                                           \
    wS = src_ - (float)i0_;                                                     \
    const float* r_ = x_emg + ((size_t)b_g * T + (rowe ? i1_ : i0_)) * CEMG;    \
    _Pragma("unroll")                                                           \
    for (int t = 0; t < 4; ++t) {                                               \
      float4 v_ = *(const float4*)(r_ + t * 4);                                 \
      gr[t * 4 + 0] = v_.x; gr[t * 4 + 1] = v_.y;                               \
      gr[t * 4 + 2] = v_.z; gr[t * 4 + 3] = v_.w;                               \
    }                                                                           \
  } } while (0)

#define LERP_WE(BUF) do { if (act) {                                            \
    const float wg_ = wS, om_ = 1.0f - wg_;                                     \
    _Pragma("unroll")                                                           \
    for (int t2 = 0; t2 < 2; ++t2) {                                            \
      float pv_[8];                                                             \
      _Pragma("unroll")                                                         \
      for (int u = 0; u < 8; ++u) pv_[u] = __shfl_xor(gr[t2 * 8 + u], 1);       \
      if (rowe == 0) {                                                          \
        bf16x8_t o_;                                                            \
        _Pragma("unroll")                                                       \
        for (int u = 0; u < 8; ++u)                                             \
          o_[u] = (__bf16)(gr[t2 * 8 + u] * om_ + pv_[u] * wg_);                \
        const int kq_ = se * 2 + t2;                                            \
        *(bf16x8_t*)(&lds[BUF][ble >> 4][kq_ >> 2]                              \
                         [((kq_ & 3) * 16 + (ble & 15)) * 8]) = o_;             \
      }                                                                         \
    }                                                                           \
  } } while (0)

#define ISSUE_BE(g1) do {                                                       \
    const __bf16* pb_ = bg + (size_t)((g1) * 3) * 512;                          \
    _Pragma("unroll")                                                           \
    for (int ks = 0; ks < 3; ++ks) {                                            \
      bB[ks * 2 + 0] = *(const bf16x8_t*)(pb_ + (size_t)ks * 512);              \
      bB[ks * 2 + 1] = *(const bf16x8_t*)(pb_ + PS + (size_t)ks * 512);         \
    }                                                                           \
  } while (0)

#define COMPUTE_E(Pp) do {                                                      \
    _Pragma("unroll")                                                           \
    for (int ks = 0; ks < 3; ++ks) {                                            \
      bf16x8_t a0_ = *(const bf16x8_t*)(&lds[Pp][0][ks][l * 8]);                \
      bf16x8_t a1_ = *(const bf16x8_t*)(&lds[Pp][1][ks][l * 8]);                \
      acc00 = mfma16(a0_, bB[ks * 2 + 0], acc00);                               \
      acc01 = mfma16(a0_, bB[ks * 2 + 1], acc01);                               \
      acc10 = mfma16(a1_, bB[ks * 2 + 0], acc10);                               \
      acc11 = mfma16(a1_, bB[ks * 2 + 1], acc11);                               \
    }                                                                           \
  } while (0)

    ISSUE_GE(0); LERP_WE(0); ISSUE_BE(0);
    __syncthreads();
    for (int p = 0; p < NG; ++p) {
      const int more = (p + 1 < NG);
      if (more) ISSUE_GE(p + 1);
      COMPUTE_E(p & 1);
      if (more) ISSUE_BE(p + 1);
      if (more) LERP_WE((p + 1) & 1);
      __syncthreads();
    }
    const int lh = l >> 4, lr = l & 15;
    float* Pb = P + (size_t)(mt * 32 + lh * 4) * NCOL + wv * 32 + lr;
#pragma unroll
    for (int jj = 0; jj < 4; ++jj) {
      Pb[(size_t)jj * NCOL] = acc00[jj];
      Pb[(size_t)jj * NCOL + 16] = acc01[jj];
      Pb[(size_t)(16 + jj) * NCOL] = acc10[jj];
      Pb[(size_t)(16 + jj) * NCOL + 16] = acc11[jj];
    }
#undef ISSUE_GE
#undef LERP_WE
#undef ISSUE_BE
#undef COMPUTE_E
  }
}

// ---------- K2: sum split-K partials + bias -> d_out
__global__ __launch_bounds__(256) void combine_kernel(
    const float* __restrict__ bias, const float* __restrict__ p_imu,
    const float* __restrict__ p_emg, float* __restrict__ out, int B) {
  const int b = blockIdx.x, m = blockIdx.y, j = threadIdx.x;
  const size_t n = (size_t)B * NCOL;
  const size_t o = (size_t)b * NCOL + j;
  if (m == 0) {
    float v = bias[j];
#pragma unroll
    for (int c = 0; c < NCI; ++c) v += p_imu[c * n + o];
    out[o] = v;
  } else {
    float v = bias[NCOL + j];
#pragma unroll
    for (int c = 0; c < NCE; ++c) v += p_emg[c * n + o];
    out[n + o] = v;
  }
}

extern "C" void kernel_launch(void* const* d_in, const int* in_sizes, int n_in,
                              void* d_out, int out_size, void* d_ws, size_t ws_size,
                              hipStream_t stream) {
  const float* x_imu     = (const float*)d_in[0];
  const float* x_emg     = (const float*)d_in[1];
  const int*   lens      = (const int*)d_in[2];
  const float* w_emb_imu = (const float*)d_in[3];
  const float* b_emb_imu = (const float*)d_in[4];
  const float* w_emb_emg = (const float*)d_in[5];
  const float* b_emb_emg = (const float*)d_in[6];
  const float* w_proj    = (const float*)d_in[7];
  const float* b_proj    = (const float*)d_in[8];
  float* out = (float*)d_out;

  const int B = in_sizes[2];
  const int T = in_sizes[0] / (B * CIMU);

  char* ws = (char*)d_ws;
  __bf16* wpk_imu = (__bf16*)ws;  ws += (size_t)NCOL * KIMU * 2;
  __bf16* wpk_emg = (__bf16*)ws;  ws += (size_t)NCOL * KEMG * 2;
  float*  bias    = (float*)ws;   ws += 2 * NCOL * 4;
  float*  bpart   = (float*)ws;   ws += (size_t)2 * NEWL * NCOL * 4;
  float*  p_imu   = (float*)ws;   ws += (size_t)NCI * B * NCOL * 4;
  float*  p_emg   = (float*)ws;   ws += (size_t)NCE * B * NCOL * 4;

  wcomb_kernel<<<dim3(NEWL, 2), 256, 0, stream>>>(
      w_emb_imu, w_emb_emg, b_emb_imu, b_emb_emg, w_proj, wpk_imu, wpk_emg, bpart);
  const int nblk = NCE * (B >> 5) + NCI * (B >> 6) + 1;  // 513
  fused_kernel<<<nblk, 512, 0, stream>>>(x_imu, x_emg, lens, wpk_imu, wpk_emg,
                                         b_proj, bpart, p_imu, p_emg, bias, B, T);
  combine_kernel<<<dim3(B, 2), 256, 0, stream>>>(bias, p_imu, p_emg, out, B);
}